// Round 1
// baseline (367.695 us; speedup 1.0000x reference)
//
#include <hip/hip_runtime.h>
#include <math.h>

// MultiHeadBigBirdAttention: B=2, S=2048, E=1024, H=8, DH=128
// Pipeline:
//   1. wtrans: Wq/Wk/Wv/Wo fp32 [K][N] -> bf16 W^T [N][K] in ws
//   2. gemm_k<1,0>: Q = q@Wq+bq  -> Qh bf16 [B,H,S,DH]
//      gemm_k<1,0>: K = k@Wk+bk  -> Kh bf16 [B,H,S,DH]
//      gemm_k<1,1>: V = v@Wv+bv  -> Vt bf16 [B,H,DH,S]   (transposed for PV frags)
//   3. flash_k: online-softmax attention -> ctx bf16 [B*S, E] (heads merged)
//   4. gemm_k<0,2>: out = ctx@Wo+bo -> d_out fp32
//
// MFMA 16x16x32 bf16. Verified layouts (learn_hip m89/m91/m120):
//   C/D: col = lane&15, row = (lane>>4)*4 + reg
//   A:   m   = lane&15, k   = (lane>>4)*8 + j
//   B:   n   = lane&15, k   = (lane>>4)*8 + j

typedef __bf16 bf16_t;
typedef __bf16 bf16x8 __attribute__((ext_vector_type(8)));
typedef float f32x4 __attribute__((ext_vector_type(4)));

#define MFMA16(a, b, c) __builtin_amdgcn_mfma_f32_16x16x32_bf16(a, b, c, 0, 0, 0)

// ---------------------------------------------------------------------------
// Weight transpose + fp32->bf16 convert: W [1024][1024] -> Wt [1024][1024]^T
// ---------------------------------------------------------------------------
__global__ __launch_bounds__(256) void wtrans(const float* W0, const float* W1,
                                              const float* W2, const float* W3,
                                              bf16_t* out) {
  const float* W = (blockIdx.z == 0) ? W0 : (blockIdx.z == 1) ? W1
                                          : (blockIdx.z == 2) ? W2 : W3;
  bf16_t* o = out + (size_t)blockIdx.z * 1024 * 1024;
  __shared__ float t[32][33];
  int n0 = blockIdx.x * 32, k0 = blockIdx.y * 32;
  int tx = threadIdx.x, ty = threadIdx.y;
#pragma unroll
  for (int i = 0; i < 4; i++) {
    t[ty + 8 * i][tx] = W[(size_t)(k0 + ty + 8 * i) * 1024 + n0 + tx];
  }
  __syncthreads();
#pragma unroll
  for (int i = 0; i < 4; i++) {
    o[(size_t)(n0 + ty + 8 * i) * 1024 + k0 + tx] = (bf16_t)t[tx][ty + 8 * i];
  }
}

// ---------------------------------------------------------------------------
// GEMM: C[M,N] = A[M,K] @ W[K,N] + bias, via Bt = W^T bf16 [N][K].
// 128x128 tile, BK=32, 4 waves (2x2), each wave 64x64 = 4x4 MFMA tiles.
// A_F32: A is fp32 (convert in staging) vs bf16.
// OUT_MODE: 0 = bf16 head layout [B,H,S,DH]; 1 = bf16 V^T layout [B,H,DH,S];
//           2 = fp32 plain [M,N].
// LDS layout [128][32] bf16 with 8-elem chunk XOR swizzle: chunk c -> c ^ ((r>>1)&3)
// ---------------------------------------------------------------------------
template <int A_F32, int OUT_MODE>
__global__ __launch_bounds__(256) void gemm_k(const void* Ap, const bf16_t* Bt,
                                              const float* bias, void* Cp,
                                              int M, int N, int K) {
  __shared__ bf16_t As[128 * 32];
  __shared__ bf16_t Bs[128 * 32];
  const int tid = threadIdx.x;
  const int bm = blockIdx.y, bn = blockIdx.x;
  const int w = tid >> 6, lane = tid & 63;
  const int wr = w >> 1, wc = w & 1;
  const int q4 = lane >> 4, lo = lane & 15;

  f32x4 acc[4][4];
#pragma unroll
  for (int m = 0; m < 4; m++)
#pragma unroll
    for (int n = 0; n < 4; n++) acc[m][n] = (f32x4){0.f, 0.f, 0.f, 0.f};

  const int r = tid >> 1, half = tid & 1;
  const int c0 = half * 2;
  const int swzr = (r >> 1) & 3;

  for (int k0 = 0; k0 < K; k0 += 32) {
    // ---- stage A (128 rows x 32 k) ----
    {
      bf16x8 v0, v1;
      if (A_F32) {
        const float* A = (const float*)Ap;
        const float* src = A + (size_t)(bm * 128 + r) * K + k0 + half * 16;
        float4 f0 = *(const float4*)(src + 0);
        float4 f1 = *(const float4*)(src + 4);
        float4 f2 = *(const float4*)(src + 8);
        float4 f3 = *(const float4*)(src + 12);
        v0 = (bf16x8){(bf16_t)f0.x, (bf16_t)f0.y, (bf16_t)f0.z, (bf16_t)f0.w,
                      (bf16_t)f1.x, (bf16_t)f1.y, (bf16_t)f1.z, (bf16_t)f1.w};
        v1 = (bf16x8){(bf16_t)f2.x, (bf16_t)f2.y, (bf16_t)f2.z, (bf16_t)f2.w,
                      (bf16_t)f3.x, (bf16_t)f3.y, (bf16_t)f3.z, (bf16_t)f3.w};
      } else {
        const bf16_t* A = (const bf16_t*)Ap;
        const bf16_t* src = A + (size_t)(bm * 128 + r) * K + k0 + half * 16;
        v0 = *(const bf16x8*)(src);
        v1 = *(const bf16x8*)(src + 8);
      }
      *(bf16x8*)&As[r * 32 + ((c0 + 0) ^ swzr) * 8] = v0;
      *(bf16x8*)&As[r * 32 + ((c0 + 1) ^ swzr) * 8] = v1;
    }
    // ---- stage B (128 n-rows x 32 k) from Bt[n][k] ----
    {
      const bf16_t* src = Bt + (size_t)(bn * 128 + r) * K + k0 + half * 16;
      bf16x8 v0 = *(const bf16x8*)(src);
      bf16x8 v1 = *(const bf16x8*)(src + 8);
      *(bf16x8*)&Bs[r * 32 + ((c0 + 0) ^ swzr) * 8] = v0;
      *(bf16x8*)&Bs[r * 32 + ((c0 + 1) ^ swzr) * 8] = v1;
    }
    __syncthreads();

    bf16x8 af[4], bf[4];
#pragma unroll
    for (int m = 0; m < 4; m++) {
      int rr = wr * 64 + m * 16 + lo;
      af[m] = *(const bf16x8*)&As[rr * 32 + (q4 ^ ((rr >> 1) & 3)) * 8];
    }
#pragma unroll
    for (int n = 0; n < 4; n++) {
      int rr = wc * 64 + n * 16 + lo;
      bf[n] = *(const bf16x8*)&Bs[rr * 32 + (q4 ^ ((rr >> 1) & 3)) * 8];
    }
#pragma unroll
    for (int m = 0; m < 4; m++)
#pragma unroll
      for (int n = 0; n < 4; n++) acc[m][n] = MFMA16(af[m], bf[n], acc[m][n]);
    __syncthreads();
  }

  // ---- epilogue ----
#pragma unroll
  for (int m = 0; m < 4; m++) {
#pragma unroll
    for (int n = 0; n < 4; n++) {
      int rowg0 = bm * 128 + wr * 64 + m * 16 + q4 * 4;
      int colg = bn * 128 + wc * 64 + n * 16 + lo;
      float bv = bias[colg];
#pragma unroll
      for (int rg = 0; rg < 4; rg++) {
        float val = acc[m][n][rg] + bv;
        int row = rowg0 + rg;
        if (OUT_MODE == 2) {
          ((float*)Cp)[(size_t)row * N + colg] = val;
        } else {
          int b = row >> 11, s = row & 2047;   // S = 2048
          int h = colg >> 7, d = colg & 127;   // DH = 128
          bf16_t* C = (bf16_t*)Cp;
          if (OUT_MODE == 0)
            C[(((size_t)(b * 8 + h)) * 2048 + s) * 128 + d] = (bf16_t)val;
          else
            C[(((size_t)(b * 8 + h)) * 128 + d) * 2048 + s] = (bf16_t)val;
        }
      }
    }
  }
}

// ---------------------------------------------------------------------------
// Flash attention: grid (S/64, B*H), block 256 (4 waves x 16 q-rows).
// Qh/Kh: [B,H,S,DH] bf16; Vt: [B,H,DH,S] bf16; ctx: [B*S, E] bf16 (merged).
// ---------------------------------------------------------------------------
__global__ __launch_bounds__(256) void flash_k(const bf16_t* Qh, const bf16_t* Kh,
                                               const bf16_t* Vt, bf16_t* ctx,
                                               const int* causal_p) {
  __shared__ bf16_t Qs[64 * 128];   // [qrow][dh], chunk swz c^(r&7)
  __shared__ bf16_t Ks[64 * 128];   // [key][dh]
  __shared__ bf16_t Vs[128 * 64];   // [dh][key]
  __shared__ bf16_t Ps[4 * 16 * 64]; // per-wave [row][key]
  const int tid = threadIdx.x;
  const int qt = blockIdx.x, bh = blockIdx.y;
  const int w = tid >> 6, lane = tid & 63;
  const int q4 = lane >> 4, lo = lane & 15;
  const int causal = *causal_p;

  // ---- stage Q tile ----
  {
    int r = tid >> 2, seg = tid & 3;
    const bf16_t* src = Qh + ((size_t)bh * 2048 + qt * 64 + r) * 128 + seg * 32;
#pragma unroll
    for (int i = 0; i < 4; i++) {
      bf16x8 vv = *(const bf16x8*)(src + i * 8);
      int c = seg * 4 + i;
      *(bf16x8*)&Qs[r * 128 + (c ^ (r & 7)) * 8] = vv;
    }
  }
  __syncthreads();

  // hoist Q A-fragments (wave's 16 rows, all 128 dh)
  bf16x8 aq[4];
  {
    int rr = w * 16 + lo;
#pragma unroll
    for (int ks = 0; ks < 4; ks++) {
      int c = ks * 4 + q4;
      aq[ks] = *(const bf16x8*)&Qs[rr * 128 + (c ^ (rr & 7)) * 8];
    }
  }

  float m_run[4], l_run[4];
  f32x4 acc[8];
#pragma unroll
  for (int i = 0; i < 4; i++) { m_run[i] = -INFINITY; l_run[i] = 0.f; }
#pragma unroll
  for (int i = 0; i < 8; i++) acc[i] = (f32x4){0.f, 0.f, 0.f, 0.f};

  const int ktmax = causal ? qt : 31;
  for (int kt = 0; kt <= ktmax; ++kt) {
    __syncthreads();  // previous iter done with Ks/Vs
    // ---- stage K tile ----
    {
      int r = tid >> 2, seg = tid & 3;
      const bf16_t* src = Kh + ((size_t)bh * 2048 + kt * 64 + r) * 128 + seg * 32;
#pragma unroll
      for (int i = 0; i < 4; i++) {
        bf16x8 vv = *(const bf16x8*)(src + i * 8);
        int c = seg * 4 + i;
        *(bf16x8*)&Ks[r * 128 + (c ^ (r & 7)) * 8] = vv;
      }
    }
    // ---- stage V^T tile ----
    {
      int d = tid >> 1, hf = tid & 1;
      const bf16_t* src = Vt + ((size_t)bh * 128 + d) * 2048 + kt * 64 + hf * 32;
#pragma unroll
      for (int i = 0; i < 4; i++) {
        bf16x8 vv = *(const bf16x8*)(src + i * 8);
        int c = hf * 4 + i;
        *(bf16x8*)&Vs[d * 64 + (c ^ (d & 7)) * 8] = vv;
      }
    }
    __syncthreads();

    // ---- scores: S = Q @ K^T (wave: 16 rows x 64 keys) ----
    f32x4 sa[4];
#pragma unroll
    for (int nt = 0; nt < 4; nt++) {
      sa[nt] = (f32x4){0.f, 0.f, 0.f, 0.f};
      int key = nt * 16 + lo;
#pragma unroll
      for (int ks = 0; ks < 4; ks++) {
        int c = ks * 4 + q4;
        bf16x8 bk = *(const bf16x8*)&Ks[key * 128 + (c ^ (key & 7)) * 8];
        sa[nt] = MFMA16(aq[ks], bk, sa[nt]);
      }
    }

    // ---- online softmax (per C/D row = q4*4+rg) ----
    const float scale = 0.08838834764831845f;  // 1/sqrt(128)
    float p[4][4];  // [nt][rg]
#pragma unroll
    for (int rg = 0; rg < 4; rg++) {
      float mx = -INFINITY;
#pragma unroll
      for (int nt = 0; nt < 4; nt++) {
        float s = sa[nt][rg] * scale;
        if (causal) {
          int rowq = qt * 64 + w * 16 + q4 * 4 + rg;
          int colk = kt * 64 + nt * 16 + lo;
          if (colk > rowq) s = -INFINITY;
        }
        p[nt][rg] = s;
        mx = fmaxf(mx, s);
      }
#pragma unroll
      for (int off = 1; off < 16; off <<= 1) mx = fmaxf(mx, __shfl_xor(mx, off));
      float mn = fmaxf(m_run[rg], mx);
      float alpha = __expf(m_run[rg] - mn);
      float sum = 0.f;
#pragma unroll
      for (int nt = 0; nt < 4; nt++) {
        float e = __expf(p[nt][rg] - mn);
        p[nt][rg] = e;
        sum += e;
      }
#pragma unroll
      for (int off = 1; off < 16; off <<= 1) sum += __shfl_xor(sum, off);
      l_run[rg] = l_run[rg] * alpha + sum;
      m_run[rg] = mn;
#pragma unroll
      for (int nt2 = 0; nt2 < 8; nt2++) acc[nt2][rg] *= alpha;
    }

    // ---- write P to LDS (C/D layout -> [row][key]) ----
#pragma unroll
    for (int nt = 0; nt < 4; nt++) {
#pragma unroll
      for (int rg = 0; rg < 4; rg++) {
        int rr = q4 * 4 + rg;
        int kk = nt * 16 + lo;
        Ps[w * 1024 + rr * 64 + (((kk >> 3) ^ (rr & 7)) * 8) + (kk & 7)] =
            (bf16_t)p[nt][rg];
      }
    }

    // ---- PV: acc += P @ V (wave: 16 rows x 128 dh, K=64 keys) ----
#pragma unroll
    for (int ks = 0; ks < 2; ks++) {
      int c = ks * 4 + q4;
      bf16x8 ap = *(const bf16x8*)&Ps[w * 1024 + lo * 64 + (c ^ (lo & 7)) * 8];
#pragma unroll
      for (int nt2 = 0; nt2 < 8; nt2++) {
        int d = nt2 * 16 + lo;
        bf16x8 bv = *(const bf16x8*)&Vs[d * 64 + (c ^ (d & 7)) * 8];
        acc[nt2] = MFMA16(ap, bv, acc[nt2]);
      }
    }
  }

  // ---- epilogue: ctx[t][h*128 + d] = acc / l ----
  int b = bh >> 3, h = bh & 7;
#pragma unroll
  for (int rg = 0; rg < 4; rg++) {
    float inv = 1.f / l_run[rg];
    int t = b * 2048 + qt * 64 + w * 16 + q4 * 4 + rg;
#pragma unroll
    for (int nt2 = 0; nt2 < 8; nt2++) {
      ctx[(size_t)t * 1024 + h * 128 + nt2 * 16 + lo] =
          (bf16_t)(acc[nt2][rg] * inv);
    }
  }
}

// ---------------------------------------------------------------------------
extern "C" void kernel_launch(void* const* d_in, const int* in_sizes, int n_in,
                              void* d_out, int out_size, void* d_ws,
                              size_t ws_size, hipStream_t stream) {
  const float* q = (const float*)d_in[0];
  const float* k = (const float*)d_in[1];
  const float* v = (const float*)d_in[2];
  const float* Wq = (const float*)d_in[3];
  const float* bq = (const float*)d_in[4];
  const float* Wk = (const float*)d_in[5];
  const float* bk = (const float*)d_in[6];
  const float* Wv = (const float*)d_in[7];
  const float* bv = (const float*)d_in[8];
  const float* Wo = (const float*)d_in[9];
  const float* bo = (const float*)d_in[10];
  const int* isc = (const int*)d_in[11];

  char* ws = (char*)d_ws;
  bf16_t* Wt = (bf16_t*)ws;                      // 4 x 2MB (W^T bf16)
  bf16_t* Qh = (bf16_t*)(ws + (8ull << 20));     // 8MB [B,H,S,DH]
  bf16_t* Kh = (bf16_t*)(ws + (16ull << 20));    // 8MB [B,H,S,DH]
  bf16_t* Vt = (bf16_t*)(ws + (24ull << 20));    // 8MB [B,H,DH,S]
  bf16_t* ctx = (bf16_t*)(ws + (32ull << 20));   // 8MB [B*S, E]

  wtrans<<<dim3(32, 32, 4), dim3(32, 8), 0, stream>>>(Wq, Wk, Wv, Wo, Wt);

  dim3 gg(8, 32);  // (N/128, M/128)
  gemm_k<1, 0><<<gg, 256, 0, stream>>>(q, Wt + (0ull << 20), bq, Qh, 4096, 1024, 1024);
  gemm_k<1, 0><<<gg, 256, 0, stream>>>(k, Wt + (1ull << 20), bk, Kh, 4096, 1024, 1024);
  gemm_k<1, 1><<<gg, 256, 0, stream>>>(v, Wt + (2ull << 20), bv, Vt, 4096, 1024, 1024);

  flash_k<<<dim3(32, 16), 256, 0, stream>>>(Qh, Kh, Vt, ctx, isc);

  gemm_k<0, 2><<<gg, 256, 0, stream>>>(ctx, Wt + (3ull << 20), bo, d_out, 4096, 1024, 1024);
}